// Round 2
// baseline (781.414 us; speedup 1.0000x reference)
//
#include <hip/hip_runtime.h>
#include <cstddef>
#include <cstdint>

typedef unsigned short u16;

constexpr int BATCH = 4;
constexpr int Lq = 4096;
constexpr int Lk = 4096;
constexpr int D  = 512;

constexpr int BM = 128, BN = 128, BK = 32;
constexpr int LDA = 40;   // fallback-path LDS stride

using bf16x8 = __attribute__((ext_vector_type(8))) short;
using f32x4  = __attribute__((ext_vector_type(4))) float;

__device__ inline u16 f32_to_bf16_rne(float x) {
    uint32_t u = __builtin_bit_cast(uint32_t, x);
    u += 0x7fff + ((u >> 16) & 1);
    return (u16)(u >> 16);
}
__device__ inline float bf16_bits_to_f32(u16 h) {
    uint32_t u = ((uint32_t)h) << 16;
    return __builtin_bit_cast(float, u);
}
__device__ inline void split2(float x, float y, uint32_t& hi, uint32_t& lo) {
    u16 hx = f32_to_bf16_rne(x);
    u16 hy = f32_to_bf16_rne(y);
    u16 lx = f32_to_bf16_rne(x - bf16_bits_to_f32(hx));
    u16 ly = f32_to_bf16_rne(y - bf16_bits_to_f32(hy));
    hi = (uint32_t)hx | ((uint32_t)hy << 16);
    lo = (uint32_t)lx | ((uint32_t)ly << 16);
}
__device__ inline uint32_t pack2_bf16(float x, float y) {
    return (uint32_t)f32_to_bf16_rne(x) | ((uint32_t)f32_to_bf16_rne(y) << 16);
}
// async global->LDS, 16B/lane; LDS dest is wave-uniform base + lane*16
__device__ inline void gld16(const u16* g, u16* l) {
    __builtin_amdgcn_global_load_lds(
        (const __attribute__((address_space(1))) void*)g,
        (__attribute__((address_space(3))) void*)l, 16, 0, 0);
}
__device__ inline f32x4 mfma16(bf16x8 a, bf16x8 b, f32x4 c) {
    return __builtin_amdgcn_mfma_f32_16x16x32_bf16(a, b, c, 0, 0, 0);
}

// ---------------- pre-split: fp32 -> bf16 hi + bf16 lo ---------------------
__global__ __launch_bounds__(256)
void split_bf16(const float* __restrict__ src, u16* __restrict__ hi,
                u16* __restrict__ lo, int n4)
{
    const int i = blockIdx.x * 256 + threadIdx.x;
    if (i >= n4) return;
    const float4 v = ((const float4*)src)[i];
    uint2 h, l;
    split2(v.x, v.y, h.x, l.x);
    split2(v.z, v.w, h.y, l.y);
    ((uint2*)hi)[i] = h;
    ((uint2*)lo)[i] = l;
}

// ---------------- V^T (bf16) into workspace: VT[b][d][lk] -------------------
__global__ __launch_bounds__(256)
void transpose_v_bf16(const float* __restrict__ V, u16* __restrict__ VT)
{
    __shared__ float tile[32][33];
    const int b = blockIdx.z;
    const float* in = V + (size_t)b * Lk * D;
    u16* out = VT + (size_t)b * D * Lk;
    const int lk0 = blockIdx.x * 32;
    const int d0  = blockIdx.y * 32;
    const int c  = threadIdx.x & 31;
    const int r0 = threadIdx.x >> 5;
    #pragma unroll
    for (int i = 0; i < 4; ++i) {
        const int r = r0 + 8 * i;
        tile[r][c] = in[(size_t)(lk0 + r) * D + d0 + c];
    }
    __syncthreads();
    #pragma unroll
    for (int i = 0; i < 4; ++i) {
        const int r = r0 + 8 * i;
        out[(size_t)(d0 + r) * Lk + lk0 + c] = f32_to_bf16_rne(tile[c][r]);
    }
}

// ===== GEMM1: S = Q@V^T, 256x256 tile, 8 waves, 4-phase/K-tile pipeline ====
// hi/lo bf16 triple-product; T2 XOR-swizzle (both-sides), T3/T4 counted
// prefetch, T5 setprio. Epilogue computes per-(row, col-block) softmax
// partials (max, sumexp) from the registers -> Mw/Sw, saving a full
// re-read of S in the softmax pass.
__global__ __launch_bounds__(512, 2)
void gemm1_8p(const u16* __restrict__ Qhi, const u16* __restrict__ Qlo,
              const u16* __restrict__ Vhi, const u16* __restrict__ Vlo,
              float* __restrict__ Sg, float* __restrict__ Mw,
              float* __restrict__ Sw)
{
    constexpr int K  = D;        // 512
    constexpr int NT = K / 32;   // 16 K-tiles
    // [buf][Ahi|Alo|Bhi|Blo][256 rows][32 k] u16 = 128 KiB
    __shared__ u16 lds[2 * 4 * 8192];

    const int b = blockIdx.z;
    const u16* Ah = Qhi + (size_t)b * Lq * K;
    const u16* Al = Qlo + (size_t)b * Lq * K;
    const u16* Bh = Vhi + (size_t)b * Lk * K;
    const u16* Bl = Vlo + (size_t)b * Lk * K;
    float* C = Sg + (size_t)b * Lq * Lk;

    // bijective XCD swizzle: 256 tiles/batch, 8 XCDs -> chunks of 32
    int id = blockIdx.y * 16 + blockIdx.x;
    id = (id & 7) * 32 + (id >> 3);
    const int m0 = (id >> 4) * 256;
    const int n0 = (id & 15) * 256;
    const int cb = id & 15;            // col-block index for stats

    const int t = threadIdx.x, lane = t & 63, w = t >> 6;
    const int wm = (w >> 2) * 128, wn = (w & 3) * 64;
    const int fr = lane & 15, fq = lane >> 4;

    // staging: LDS dest linear (gld16 = uniform base + lane*16); the XOR
    // swizzle is applied on the per-lane GLOBAL source chunk instead.
    const int cg   = (lane & 3) ^ ((lane >> 3) & 3);   // inverse-swizzled k-chunk
    const int rsub = lane >> 2;
    const int offA0 = (m0 + w * 32 + rsub) * K + cg * 8;
    const int offA1 = offA0 + 16 * K;
    const int offB0 = (n0 + w * 32 + rsub) * K + cg * 8;
    const int offB1 = offB0 + 16 * K;
    const int ch = w * 1024;   // u16: this wave's chunk base

    // fragment reads: same XOR on the read side -> conflict-free 2-way
    const int swzc = fq ^ ((fr >> 1) & 3);
    const int aRd = (wm + fr) * 64 + swzc * 16;   // bytes within Ahi region
    const int bRd = (wn + fr) * 64 + swzc * 16;   // bytes within Bhi region

    f32x4 acc[8][4] = {};
    bf16x8 aH[4], aL[4], bH[4], bL[4];

    // prologue: stage K-tile 0 into buf 0
    {
        u16* a = &lds[ch];
        gld16(Ah + offA0, a);
        gld16(Ah + offA1, a + 512);
        gld16(Al + offA0, a + 8192);
        gld16(Al + offA1, a + 8192 + 512);
        u16* v = &lds[16384 + ch];
        gld16(Bh + offB0, v);
        gld16(Bh + offB1, v + 512);
        gld16(Bl + offB0, v + 8192);
        gld16(Bl + offB1, v + 8192 + 512);
    }
    asm volatile("s_waitcnt vmcnt(0)" ::: "memory");
    __builtin_amdgcn_s_barrier();
    __builtin_amdgcn_sched_barrier(0);

    for (int kt = 0; kt < NT; ++kt) {
        const int cur = kt & 1;
        const char* ls = (const char*)lds + cur * 65536;
        const int kn = (kt + 1) * 32;
        const int nb = (cur ^ 1) * 32768;   // u16 index of next buffer

        // ---- phase 0: frags A(mh0) + B(n0,n1); prefetch next A ----
        #pragma unroll
        for (int m = 0; m < 4; ++m) {
            aH[m] = *(const bf16x8*)(ls + aRd + m * 1024);
            aL[m] = *(const bf16x8*)(ls + 16384 + aRd + m * 1024);
        }
        #pragma unroll
        for (int n = 0; n < 2; ++n) {
            bH[n] = *(const bf16x8*)(ls + 32768 + bRd + n * 1024);
            bL[n] = *(const bf16x8*)(ls + 49152 + bRd + n * 1024);
        }
        if (kt < NT - 1) {
            u16* a = &lds[nb + ch];
            gld16(Ah + offA0 + kn, a);
            gld16(Ah + offA1 + kn, a + 512);
            gld16(Al + offA0 + kn, a + 8192);
            gld16(Al + offA1 + kn, a + 8192 + 512);
        }
        __builtin_amdgcn_s_barrier();
        asm volatile("s_waitcnt lgkmcnt(0)" ::: "memory");
        __builtin_amdgcn_sched_barrier(0);
        __builtin_amdgcn_s_setprio(1);
        #pragma unroll
        for (int m = 0; m < 4; ++m)
            #pragma unroll
            for (int n = 0; n < 2; ++n) {
                acc[m][n] = mfma16(aH[m], bH[n], acc[m][n]);
                acc[m][n] = mfma16(aH[m], bL[n], acc[m][n]);
                acc[m][n] = mfma16(aL[m], bH[n], acc[m][n]);
            }
        __builtin_amdgcn_s_setprio(0);
        __builtin_amdgcn_s_barrier();
        __builtin_amdgcn_sched_barrier(0);

        // ---- phase 1: frags B(n2,n3); prefetch next B ----
        #pragma unroll
        for (int n = 2; n < 4; ++n) {
            bH[n] = *(const bf16x8*)(ls + 32768 + bRd + n * 1024);
            bL[n] = *(const bf16x8*)(ls + 49152 + bRd + n * 1024);
        }
        if (kt < NT - 1) {
            u16* v = &lds[nb + 16384 + ch];
            gld16(Bh + offB0 + kn, v);
            gld16(Bh + offB1 + kn, v + 512);
            gld16(Bl + offB0 + kn, v + 8192);
            gld16(Bl + offB1 + kn, v + 8192 + 512);
        }
        __builtin_amdgcn_s_barrier();
        asm volatile("s_waitcnt lgkmcnt(0)" ::: "memory");
        __builtin_amdgcn_sched_barrier(0);
        __builtin_amdgcn_s_setprio(1);
        #pragma unroll
        for (int m = 0; m < 4; ++m)
            #pragma unroll
            for (int n = 2; n < 4; ++n) {
                acc[m][n] = mfma16(aH[m], bH[n], acc[m][n]);
                acc[m][n] = mfma16(aH[m], bL[n], acc[m][n]);
                acc[m][n] = mfma16(aL[m], bH[n], acc[m][n]);
            }
        __builtin_amdgcn_s_setprio(0);
        __builtin_amdgcn_s_barrier();
        __builtin_amdgcn_sched_barrier(0);

        // ---- phase 2: frags A(mh1) ----
        #pragma unroll
        for (int m = 0; m < 4; ++m) {
            aH[m] = *(const bf16x8*)(ls + 4096 + aRd + m * 1024);
            aL[m] = *(const bf16x8*)(ls + 16384 + 4096 + aRd + m * 1024);
        }
        __builtin_amdgcn_s_barrier();
        asm volatile("s_waitcnt lgkmcnt(0)" ::: "memory");
        __builtin_amdgcn_sched_barrier(0);
        __builtin_amdgcn_s_setprio(1);
        #pragma unroll
        for (int m = 0; m < 4; ++m)
            #pragma unroll
            for (int n = 0; n < 2; ++n) {
                acc[4 + m][n] = mfma16(aH[m], bH[n], acc[4 + m][n]);
                acc[4 + m][n] = mfma16(aH[m], bL[n], acc[4 + m][n]);
                acc[4 + m][n] = mfma16(aL[m], bH[n], acc[4 + m][n]);
            }
        __builtin_amdgcn_s_setprio(0);
        __builtin_amdgcn_s_barrier();
        __builtin_amdgcn_sched_barrier(0);

        // ---- phase 3: last quadrant; tile-boundary drain (only vmcnt) ----
        __builtin_amdgcn_s_setprio(1);
        #pragma unroll
        for (int m = 0; m < 4; ++m)
            #pragma unroll
            for (int n = 2; n < 4; ++n) {
                acc[4 + m][n] = mfma16(aH[m], bH[n], acc[4 + m][n]);
                acc[4 + m][n] = mfma16(aH[m], bL[n], acc[4 + m][n]);
                acc[4 + m][n] = mfma16(aL[m], bH[n], acc[4 + m][n]);
            }
        __builtin_amdgcn_s_setprio(0);
        asm volatile("s_waitcnt vmcnt(0)" ::: "memory");
        __builtin_amdgcn_s_barrier();
        __builtin_amdgcn_sched_barrier(0);
    }

    // ---- C write (raw S) ----
    const int rowb = m0 + wm + fq * 4;
    const int colb = n0 + wn + fr;
    #pragma unroll
    for (int mi = 0; mi < 8; ++mi)
        #pragma unroll
        for (int ni = 0; ni < 4; ++ni)
            #pragma unroll
            for (int r = 0; r < 4; ++r)
                C[(size_t)(rowb + mi * 16 + r) * Lk + colb + ni * 16] = acc[mi][ni][r];

    // ---- per-row softmax partials over this block's 256 cols ----
    __syncthreads();                      // LDS no longer needed by main loop
    float* mxl = (float*)lds;             // [256][4]
    float* sml = mxl + 1024;              // [256][4]
    #pragma unroll
    for (int mi = 0; mi < 8; ++mi)
        #pragma unroll
        for (int r = 0; r < 4; ++r) {
            float mx = fmaxf(fmaxf(acc[mi][0][r], acc[mi][1][r]),
                             fmaxf(acc[mi][2][r], acc[mi][3][r]));
            #pragma unroll
            for (int off = 1; off < 16; off <<= 1)
                mx = fmaxf(mx, __shfl_xor(mx, off));
            float sm = 0.f;
            #pragma unroll
            for (int ni = 0; ni < 4; ++ni)
                sm += __expf(acc[mi][ni][r] - mx);
            #pragma unroll
            for (int off = 1; off < 16; off <<= 1)
                sm += __shfl_xor(sm, off);
            if (fr == 0) {
                const int row = wm + mi * 16 + fq * 4 + r;
                mxl[row * 4 + (w & 3)] = mx;
                sml[row * 4 + (w & 3)] = sm;
            }
        }
    __syncthreads();
    if (t < 256) {
        const float m1 = fmaxf(fmaxf(mxl[t * 4 + 0], mxl[t * 4 + 1]),
                               fmaxf(mxl[t * 4 + 2], mxl[t * 4 + 3]));
        float s1 = 0.f;
        #pragma unroll
        for (int i = 0; i < 4; ++i)
            s1 += sml[t * 4 + i] * __expf(mxl[t * 4 + i] - m1);
        const size_t ix = ((size_t)b * Lq + m0 + t) * 16 + cb;
        Mw[ix] = m1;
        Sw[ix] = s1;
    }
}

// ---- fold 16 col-block partials per row into rowM / rowInv ----------------
__global__ __launch_bounds__(256)
void reduce_stats(const float* __restrict__ Mw, const float* __restrict__ Sw,
                  float* __restrict__ rowM, float* __restrict__ rowI)
{
    const int row = blockIdx.x * 256 + threadIdx.x;   // < BATCH*Lq
    const float* mp = Mw + (size_t)row * 16;
    const float* sp = Sw + (size_t)row * 16;
    float m = mp[0];
    #pragma unroll
    for (int i = 1; i < 16; ++i) m = fmaxf(m, mp[i]);
    float s = 0.f;
    #pragma unroll
    for (int i = 0; i < 16; ++i) s += sp[i] * __expf(mp[i] - m);
    rowM[row] = m;
    rowI[row] = 1.0f / s;
}

// ---- finalize: pure streaming pass, S -> softmax(S) (fp32) + Pb (bf16) ----
__global__ __launch_bounds__(256)
void finalize_softmax(float* __restrict__ S, u16* __restrict__ Pb,
                      const float* __restrict__ rowM, const float* __restrict__ rowI)
{
    const size_t row = blockIdx.x;
    float* p = S + row * (size_t)Lk;
    u16* prow = Pb + row * (size_t)Lk;
    const int t = threadIdx.x;
    const float m = rowM[row], inv = rowI[row];
    #pragma unroll
    for (int i = 0; i < 4; ++i) {
        float4 v = ((const float4*)p)[t + i * 256];
        v.x = __expf(v.x - m) * inv;
        v.y = __expf(v.y - m) * inv;
        v.z = __expf(v.z - m) * inv;
        v.w = __expf(v.w - m) * inv;
        ((float4*)p)[t + i * 256] = v;
        ushort4 h = make_ushort4(f32_to_bf16_rne(v.x), f32_to_bf16_rne(v.y),
                                 f32_to_bf16_rne(v.z), f32_to_bf16_rne(v.w));
        ((ushort4*)prow)[t + i * 256] = h;
    }
}

// -------- softmax rows in place (fallback path only) -----------------------
__global__ __launch_bounds__(256)
void softmax_inplace(float* __restrict__ S, u16* __restrict__ Pb)
{
    const size_t row = blockIdx.x;
    float* p = S + row * (size_t)Lk;
    const int t = threadIdx.x;

    float4 v[4];
    #pragma unroll
    for (int i = 0; i < 4; ++i) v[i] = ((const float4*)p)[t + i * 256];

    float m = -3.0e38f;
    #pragma unroll
    for (int i = 0; i < 4; ++i)
        m = fmaxf(m, fmaxf(fmaxf(v[i].x, v[i].y), fmaxf(v[i].z, v[i].w)));
    #pragma unroll
    for (int off = 32; off > 0; off >>= 1) m = fmaxf(m, __shfl_xor(m, off));
    __shared__ float redm[4];
    if ((t & 63) == 0) redm[t >> 6] = m;
    __syncthreads();
    m = fmaxf(fmaxf(redm[0], redm[1]), fmaxf(redm[2], redm[3]));

    float s = 0.f;
    #pragma unroll
    for (int i = 0; i < 4; ++i) {
        v[i].x = __expf(v[i].x - m); s += v[i].x;
        v[i].y = __expf(v[i].y - m); s += v[i].y;
        v[i].z = __expf(v[i].z - m); s += v[i].z;
        v[i].w = __expf(v[i].w - m); s += v[i].w;
    }
    #pragma unroll
    for (int off = 32; off > 0; off >>= 1) s += __shfl_xor(s, off);
    __shared__ float reds[4];
    if ((t & 63) == 0) reds[t >> 6] = s;
    __syncthreads();
    s = (reds[0] + reds[1]) + (reds[2] + reds[3]);

    const float inv = 1.0f / s;
    u16* prow = Pb ? Pb + row * (size_t)Lk : nullptr;
    #pragma unroll
    for (int i = 0; i < 4; ++i) {
        v[i].x *= inv; v[i].y *= inv; v[i].z *= inv; v[i].w *= inv;
        ((float4*)p)[t + i * 256] = v[i];
        if (prow) {
            ushort4 h = make_ushort4(f32_to_bf16_rne(v[i].x), f32_to_bf16_rne(v[i].y),
                                     f32_to_bf16_rne(v[i].z), f32_to_bf16_rne(v[i].w));
            ((ushort4*)prow)[t + i * 256] = h;
        }
    }
}

// ------ GEMM2: ctx = P @ V, pure bf16 NT (Pb [Lq][Lk], VT [D][Lk]) ---------
__global__ __launch_bounds__(256, 3)
void gemm2_mfma(const u16* __restrict__ Pg, const u16* __restrict__ VTg,
                float* __restrict__ Cg)
{
    constexpr int K = Lk;   // 4096
    constexpr int N = D;    // 512
    __shared__ u16 sA[BM * BK];
    __shared__ u16 sB[BN * BK];

    const int b = blockIdx.z;
    const u16* A  = Pg  + (size_t)b * Lq * Lk;
    const u16* Bp = VTg + (size_t)b * (size_t)D * Lk;
    float* C = Cg + (size_t)b * Lq * D;

    // bijective XCD swizzle: 128 tiles/batch -> chunks of 16
    int id = blockIdx.y * 4 + blockIdx.x;
    id = (id & 7) * 16 + (id >> 3);
    const int m0 = (id >> 2) * BM;
    const int n0 = (id & 3) * BN;

    const int t = threadIdx.x, lane = t & 63, wave = t >> 6;
    const int wm = (wave >> 1) * 64, wn = (wave & 1) * 64;
    const int fr = lane & 15, fq = lane >> 4;

    const int r0  = wave * 16 + (lane >> 2);
    const int r1  = r0 + 64;
    const int kc8 = (lane & 3) * 8;
    const int oA0 = (m0 + r0) * K + kc8;
    const int oA1 = (m0 + r1) * K + kc8;
    const int oB0 = (n0 + r0) * K + kc8;
    const int oB1 = (n0 + r1) * K + kc8;
    const int w0 = wave * 512, w1 = (wave + 4) * 512;

    f32x4 acc[4][4] = {};

    for (int k0 = 0; k0 < K; k0 += BK) {
        if (k0) __syncthreads();
        gld16(A  + oA0 + k0, &sA[w0]);
        gld16(A  + oA1 + k0, &sA[w1]);
        gld16(Bp + oB0 + k0, &sB[w0]);
        gld16(Bp + oB1 + k0, &sB[w1]);
        __syncthreads();

        bf16x8 af[4], bf[4];
        #pragma unroll
        for (int x = 0; x < 4; ++x) {
            af[x] = *(const bf16x8*)&sA[(wm + x * 16 + fr) * BK + fq * 8];
            bf[x] = *(const bf16x8*)&sB[(wn + x * 16 + fr) * BK + fq * 8];
        }
        #pragma unroll
        for (int mi = 0; mi < 4; ++mi)
            #pragma unroll
            for (int ni = 0; ni < 4; ++ni)
                acc[mi][ni] = __builtin_amdgcn_mfma_f32_16x16x32_bf16(af[mi], bf[ni], acc[mi][ni], 0, 0, 0);
    }

    #pragma unroll
    for (int mi = 0; mi < 4; ++mi)
        #pragma unroll
        for (int ni = 0; ni < 4; ++ni)
            #pragma unroll
            for (int r = 0; r < 4; ++r) {
                const int row = m0 + wm + mi * 16 + fq * 4 + r;
                const int col = n0 + wn + ni * 16 + fr;
                C[(size_t)row * N + col] = acc[mi][ni][r];
            }
}

// ======================= round-2 fallback kernels ==========================
__global__ __launch_bounds__(256, 2)
void gemm1_r2(const float* __restrict__ Qg, const float* __restrict__ Vg,
              float* __restrict__ Sg)
{
    constexpr int K = D;
    __shared__ alignas(16) u16 sAhi[BM * LDA];
    __shared__ alignas(16) u16 sAlo[BM * LDA];
    __shared__ alignas(16) u16 sBhi[BN * LDA];
    __shared__ alignas(16) u16 sBlo[BN * LDA];

    const int b = blockIdx.z;
    const float* A  = Qg + (size_t)b * Lq * D;
    const float* Bp = Vg + (size_t)b * Lk * D;
    float* C = Sg + (size_t)b * Lq * Lk;

    const int m0 = blockIdx.y * BM;
    const int n0 = blockIdx.x * BN;
    const int t = threadIdx.x, lane = t & 63, wave = t >> 6;
    const int wm = (wave >> 1) * 64, wn = (wave & 1) * 64;
    const int fr = lane & 15, fq = lane >> 4;
    const int sm = t >> 3, sc = t & 7;

    f32x4 acc[4][4] = {};

    for (int k0 = 0; k0 < K; k0 += BK) {
        if (k0) __syncthreads();
        #pragma unroll
        for (int i = 0; i < 4; ++i) {
            const int m = sm + 32 * i;
            const float4 va = *(const float4*)(A  + (size_t)(m0 + m) * K + k0 + sc * 4);
            const float4 vb = *(const float4*)(Bp + (size_t)(n0 + m) * K + k0 + sc * 4);
            uint2 h, l;
            split2(va.x, va.y, h.x, l.x);
            split2(va.z, va.w, h.y, l.y);
            *(uint2*)&sAhi[m * LDA + sc * 4] = h;
            *(uint2*)&sAlo[m * LDA + sc * 4] = l;
            split2(vb.x, vb.y, h.x, l.x);
            split2(vb.z, vb.w, h.y, l.y);
            *(uint2*)&sBhi[m * LDA + sc * 4] = h;
            *(uint2*)&sBlo[m * LDA + sc * 4] = l;
        }
        __syncthreads();

        bf16x8 ah[4], al[4], bh[4], bl[4];
        #pragma unroll
        for (int x = 0; x < 4; ++x) {
            ah[x] = *(const bf16x8*)&sAhi[(wm + x * 16 + fr) * LDA + fq * 8];
            al[x] = *(const bf16x8*)&sAlo[(wm + x * 16 + fr) * LDA + fq * 8];
            bh[x] = *(const bf16x8*)&sBhi[(wn + x * 16 + fr) * LDA + fq * 8];
            bl[x] = *(const bf16x8*)&sBlo[(wn + x * 16 + fr) * LDA + fq * 8];
        }
        #pragma unroll
        for (int mi = 0; mi < 4; ++mi)
            #pragma unroll
            for (int ni = 0; ni < 4; ++ni) {
                acc[mi][ni] = __builtin_amdgcn_mfma_f32_16x16x32_bf16(ah[mi], bh[ni], acc[mi][ni], 0, 0, 0);
                acc[mi][ni] = __builtin_amdgcn_mfma_f32_16x16x32_bf16(ah[mi], bl[ni], acc[mi][ni], 0, 0, 0);
                acc[mi][ni] = __builtin_amdgcn_mfma_f32_16x16x32_bf16(al[mi], bh[ni], acc[mi][ni], 0, 0, 0);
            }
    }

    #pragma unroll
    for (int mi = 0; mi < 4; ++mi)
        #pragma unroll
        for (int ni = 0; ni < 4; ++ni)
            #pragma unroll
            for (int r = 0; r < 4; ++r) {
                const int row = m0 + wm + mi * 16 + fq * 4 + r;
                const int col = n0 + wn + ni * 16 + fr;
                C[(size_t)row * Lk + col] = acc[mi][ni][r];
            }
}

__global__ __launch_bounds__(256, 2)
void gemm2_r2(const float* __restrict__ Pg, const u16* __restrict__ VTg,
              float* __restrict__ Cg)
{
    constexpr int K = Lk;
    constexpr int N = D;
    __shared__ alignas(16) u16 sA[BM * LDA];
    __shared__ alignas(16) u16 sB[BN * LDA];

    const int b = blockIdx.z;
    const float* A  = Pg  + (size_t)b * Lq * Lk;
    const u16*   Bp = VTg + (size_t)b * (size_t)D * Lk;
    float* C = Cg + (size_t)b * Lq * D;

    const int m0 = blockIdx.y * BM;
    const int n0 = blockIdx.x * BN;
    const int t = threadIdx.x, lane = t & 63, wave = t >> 6;
    const int wm = (wave >> 1) * 64, wn = (wave & 1) * 64;
    const int fr = lane & 15, fq = lane >> 4;
    const int sm = t >> 3, sc = t & 7;
    const int bn = t >> 2, bc = t & 3;

    f32x4 acc[4][4] = {};

    for (int k0 = 0; k0 < K; k0 += BK) {
        if (k0) __syncthreads();
        #pragma unroll
        for (int i = 0; i < 4; ++i) {
            const int m = sm + 32 * i;
            const float4 va = *(const float4*)(A + (size_t)(m0 + m) * K + k0 + sc * 4);
            uint2 h;
            h.x = pack2_bf16(va.x, va.y);
            h.y = pack2_bf16(va.z, va.w);
            *(uint2*)&sA[m * LDA + sc * 4] = h;
        }
        #pragma unroll
        for (int i = 0; i < 2; ++i) {
            const int n = bn + 64 * i;
            const bf16x8 vb = *(const bf16x8*)(Bp + (size_t)(n0 + n) * K + k0 + bc * 8);
            *(bf16x8*)&sB[n * LDA + bc * 8] = vb;
        }
        __syncthreads();

        bf16x8 af[4], bf[4];
        #pragma unroll
        for (int x = 0; x < 4; ++x) {
            af[x] = *(const bf16x8*)&sA[(wm + x * 16 + fr) * LDA + fq * 8];
            bf[x] = *(const bf16x8*)&sB[(wn + x * 16 + fr) * LDA + fq * 8];
        }
        #pragma unroll
        for (int mi = 0; mi < 4; ++mi)
            #pragma unroll
            for (int ni = 0; ni < 4; ++ni)
                acc[mi][ni] = __builtin_amdgcn_mfma_f32_16x16x32_bf16(af[mi], bf[ni], acc[mi][ni], 0, 0, 0);
    }

    #pragma unroll
    for (int mi = 0; mi < 4; ++mi)
        #pragma unroll
        for (int ni = 0; ni < 4; ++ni)
            #pragma unroll
            for (int r = 0; r < 4; ++r) {
                const int row = m0 + wm + mi * 16 + fq * 4 + r;
                const int col = n0 + wn + ni * 16 + fr;
                C[(size_t)row * N + col] = acc[mi][ni][r];
            }
}

extern "C" void kernel_launch(void* const* d_in, const int* in_sizes, int n_in,
                              void* d_out, int out_size, void* d_ws, size_t ws_size,
                              hipStream_t stream)
{
    const float* Q = (const float*)d_in[0];   // [B, Lq, D]
    const float* V = (const float*)d_in[1];   // [B, Lk, D]
    float* ctx  = (float*)d_out;                              // [B, Lq, D]
    float* attn = (float*)d_out + (size_t)BATCH * Lq * D;     // [B, Lq, Lk]

    constexpr size_t NQ = (size_t)BATCH * Lq * D;    // 8,388,608 elems
    constexpr size_t NP = (size_t)BATCH * Lq * Lk;   // 67,108,864 elems
    const size_t need = (5 * NQ + NP) * sizeof(u16); // ~208 MiB

    if (ws_size >= need) {
        u16* Qhi = (u16*)d_ws;
        u16* Qlo = Qhi + NQ;
        u16* Vhi = Qlo + NQ;
        u16* Vlo = Vhi + NQ;
        u16* VT  = Vlo + NQ;
        u16* Pb  = VT  + NQ;

        // stats aliases (lifetimes don't overlap their hosts):
        //  Mw/Sw (2 MiB)  -> head of Pb region (written by gemm1, read by
        //                    reduce_stats; dead before finalize writes Pb)
        //  rowM/rowI (128 KiB) -> head of Qhi region (written after gemm1
        //                    is done with Qhi; read only by finalize)
        float* Mw   = (float*)Pb;
        float* Sw   = Mw + (size_t)BATCH * Lq * 16;
        float* rowM = (float*)Qhi;
        float* rowI = rowM + (size_t)BATCH * Lq;

        const int n4 = (int)(NQ / 4);
        split_bf16<<<dim3(n4 / 256), 256, 0, stream>>>(Q, Qhi, Qlo, n4);
        split_bf16<<<dim3(n4 / 256), 256, 0, stream>>>(V, Vhi, Vlo, n4);
        transpose_v_bf16<<<dim3(Lk / 32, D / 32, BATCH), 256, 0, stream>>>(V, VT);
        gemm1_8p<<<dim3(Lk / 256, Lq / 256, BATCH), 512, 0, stream>>>(Qhi, Qlo, Vhi, Vlo, attn, Mw, Sw);
        reduce_stats<<<dim3(BATCH * Lq / 256), 256, 0, stream>>>(Mw, Sw, rowM, rowI);
        finalize_softmax<<<dim3(BATCH * Lq), 256, 0, stream>>>(attn, Pb, rowM, rowI);
        gemm2_mfma<<<dim3(D / BN, Lq / BM, BATCH), 256, 0, stream>>>(Pb, VT, ctx);
    } else {
        // round-2 fallback: only needs 16.8 MiB for VT
        u16* VT = (u16*)d_ws;
        transpose_v_bf16<<<dim3(Lk / 32, D / 32, BATCH), 256, 0, stream>>>(V, VT);
        gemm1_r2<<<dim3(Lk / BN, Lq / BM, BATCH), 256, 0, stream>>>(Q, V, attn);
        softmax_inplace<<<dim3(BATCH * Lq), 256, 0, stream>>>(attn, nullptr);
        gemm2_r2<<<dim3(D / BN, Lq / BM, BATCH), 256, 0, stream>>>(attn, VT, ctx);
    }
}

// Round 3
// 727.027 us; speedup vs baseline: 1.0748x; 1.0748x over previous
//
#include <hip/hip_runtime.h>
#include <cstddef>
#include <cstdint>

typedef unsigned short u16;

constexpr int BATCH = 4;
constexpr int Lq = 4096;
constexpr int Lk = 4096;
constexpr int D  = 512;

constexpr int BM = 128, BN = 128, BK = 32;
constexpr int LDA = 40;   // fallback-path LDS stride

using bf16x8 = __attribute__((ext_vector_type(8))) short;
using f32x4  = __attribute__((ext_vector_type(4))) float;

__device__ inline u16 f32_to_bf16_rne(float x) {
    uint32_t u = __builtin_bit_cast(uint32_t, x);
    u += 0x7fff + ((u >> 16) & 1);
    return (u16)(u >> 16);
}
__device__ inline float bf16_bits_to_f32(u16 h) {
    uint32_t u = ((uint32_t)h) << 16;
    return __builtin_bit_cast(float, u);
}
__device__ inline void split2(float x, float y, uint32_t& hi, uint32_t& lo) {
    u16 hx = f32_to_bf16_rne(x);
    u16 hy = f32_to_bf16_rne(y);
    u16 lx = f32_to_bf16_rne(x - bf16_bits_to_f32(hx));
    u16 ly = f32_to_bf16_rne(y - bf16_bits_to_f32(hy));
    hi = (uint32_t)hx | ((uint32_t)hy << 16);
    lo = (uint32_t)lx | ((uint32_t)ly << 16);
}
__device__ inline uint32_t pack2_bf16(float x, float y) {
    return (uint32_t)f32_to_bf16_rne(x) | ((uint32_t)f32_to_bf16_rne(y) << 16);
}
// async global->LDS, 16B/lane; LDS dest is wave-uniform base + lane*16
__device__ inline void gld16(const u16* g, u16* l) {
    __builtin_amdgcn_global_load_lds(
        (const __attribute__((address_space(1))) void*)g,
        (__attribute__((address_space(3))) void*)l, 16, 0, 0);
}
__device__ inline f32x4 mfma16(bf16x8 a, bf16x8 b, f32x4 c) {
    return __builtin_amdgcn_mfma_f32_16x16x32_bf16(a, b, c, 0, 0, 0);
}

// ------- pre-split both tensors: fp32 -> bf16 hi + bf16 lo (one launch) ----
__global__ __launch_bounds__(256)
void split_qv_bf16(const float* __restrict__ Q, const float* __restrict__ V,
                   u16* __restrict__ Qhi, u16* __restrict__ Qlo,
                   u16* __restrict__ Vhi, u16* __restrict__ Vlo, int n4)
{
    int i = blockIdx.x * 256 + threadIdx.x;
    const float* src;
    u16 *hi, *lo;
    if (i < n4) { src = Q; hi = Qhi; lo = Qlo; }
    else        { src = V; hi = Vhi; lo = Vlo; i -= n4; }
    const float4 v = ((const float4*)src)[i];
    uint2 h, l;
    split2(v.x, v.y, h.x, l.x);
    split2(v.z, v.w, h.y, l.y);
    ((uint2*)hi)[i] = h;
    ((uint2*)lo)[i] = l;
}

// ---------------- V^T (bf16) into workspace: VT[b][d][lk] -------------------
__global__ __launch_bounds__(256)
void transpose_v_bf16(const float* __restrict__ V, u16* __restrict__ VT)
{
    __shared__ float tile[32][33];
    const int b = blockIdx.z;
    const float* in = V + (size_t)b * Lk * D;
    u16* out = VT + (size_t)b * D * Lk;
    const int lk0 = blockIdx.x * 32;
    const int d0  = blockIdx.y * 32;
    const int c  = threadIdx.x & 31;
    const int r0 = threadIdx.x >> 5;
    #pragma unroll
    for (int i = 0; i < 4; ++i) {
        const int r = r0 + 8 * i;
        tile[r][c] = in[(size_t)(lk0 + r) * D + d0 + c];
    }
    __syncthreads();
    #pragma unroll
    for (int i = 0; i < 4; ++i) {
        const int r = r0 + 8 * i;
        out[(size_t)(d0 + r) * Lk + lk0 + c] = f32_to_bf16_rne(tile[c][r]);
    }
}

// ===== GEMM1: S = Q@V^T, 256x256 tile, 8 waves, 4-phase/K-tile pipeline ====
// (round-1 version, verified 204 us / 0 bank conflicts — no epilogue fusion)
__global__ __launch_bounds__(512, 2)
void gemm1_8p(const u16* __restrict__ Qhi, const u16* __restrict__ Qlo,
              const u16* __restrict__ Vhi, const u16* __restrict__ Vlo,
              float* __restrict__ Sg)
{
    constexpr int K  = D;        // 512
    constexpr int NT = K / 32;   // 16 K-tiles
    // [buf][Ahi|Alo|Bhi|Blo][256 rows][32 k] u16 = 128 KiB
    __shared__ u16 lds[2 * 4 * 8192];

    const int b = blockIdx.z;
    const u16* Ah = Qhi + (size_t)b * Lq * K;
    const u16* Al = Qlo + (size_t)b * Lq * K;
    const u16* Bh = Vhi + (size_t)b * Lk * K;
    const u16* Bl = Vlo + (size_t)b * Lk * K;
    float* C = Sg + (size_t)b * Lq * Lk;

    const int m0 = blockIdx.y * 256;
    const int n0 = blockIdx.x * 256;
    const int t = threadIdx.x, lane = t & 63, w = t >> 6;
    const int wm = (w >> 2) * 128, wn = (w & 3) * 64;
    const int fr = lane & 15, fq = lane >> 4;

    // staging: LDS dest linear (gld16 = uniform base + lane*16); the XOR
    // swizzle is applied on the per-lane GLOBAL source chunk instead.
    const int cg   = (lane & 3) ^ ((lane >> 3) & 3);   // inverse-swizzled k-chunk
    const int rsub = lane >> 2;
    const int offA0 = (m0 + w * 32 + rsub) * K + cg * 8;
    const int offA1 = offA0 + 16 * K;
    const int offB0 = (n0 + w * 32 + rsub) * K + cg * 8;
    const int offB1 = offB0 + 16 * K;
    const int ch = w * 1024;   // u16: this wave's chunk base

    // fragment reads: same XOR on the read side -> conflict-free 2-way
    const int swzc = fq ^ ((fr >> 1) & 3);
    const int aRd = (wm + fr) * 64 + swzc * 16;   // bytes within Ahi region
    const int bRd = (wn + fr) * 64 + swzc * 16;   // bytes within Bhi region

    f32x4 acc[8][4] = {};
    bf16x8 aH[4], aL[4], bH[4], bL[4];

    // prologue: stage K-tile 0 into buf 0
    {
        u16* a = &lds[ch];
        gld16(Ah + offA0, a);
        gld16(Ah + offA1, a + 512);
        gld16(Al + offA0, a + 8192);
        gld16(Al + offA1, a + 8192 + 512);
        u16* v = &lds[16384 + ch];
        gld16(Bh + offB0, v);
        gld16(Bh + offB1, v + 512);
        gld16(Bl + offB0, v + 8192);
        gld16(Bl + offB1, v + 8192 + 512);
    }
    asm volatile("s_waitcnt vmcnt(0)" ::: "memory");
    __builtin_amdgcn_s_barrier();
    __builtin_amdgcn_sched_barrier(0);

    for (int kt = 0; kt < NT; ++kt) {
        const int cur = kt & 1;
        const char* ls = (const char*)lds + cur * 65536;
        const int kn = (kt + 1) * 32;
        const int nb = (cur ^ 1) * 32768;   // u16 index of next buffer

        // ---- phase 0: frags A(mh0) + B(n0,n1); prefetch next A ----
        #pragma unroll
        for (int m = 0; m < 4; ++m) {
            aH[m] = *(const bf16x8*)(ls + aRd + m * 1024);
            aL[m] = *(const bf16x8*)(ls + 16384 + aRd + m * 1024);
        }
        #pragma unroll
        for (int n = 0; n < 2; ++n) {
            bH[n] = *(const bf16x8*)(ls + 32768 + bRd + n * 1024);
            bL[n] = *(const bf16x8*)(ls + 49152 + bRd + n * 1024);
        }
        if (kt < NT - 1) {
            u16* a = &lds[nb + ch];
            gld16(Ah + offA0 + kn, a);
            gld16(Ah + offA1 + kn, a + 512);
            gld16(Al + offA0 + kn, a + 8192);
            gld16(Al + offA1 + kn, a + 8192 + 512);
        }
        __builtin_amdgcn_s_barrier();
        asm volatile("s_waitcnt lgkmcnt(0)" ::: "memory");
        __builtin_amdgcn_sched_barrier(0);
        __builtin_amdgcn_s_setprio(1);
        #pragma unroll
        for (int m = 0; m < 4; ++m)
            #pragma unroll
            for (int n = 0; n < 2; ++n) {
                acc[m][n] = mfma16(aH[m], bH[n], acc[m][n]);
                acc[m][n] = mfma16(aH[m], bL[n], acc[m][n]);
                acc[m][n] = mfma16(aL[m], bH[n], acc[m][n]);
            }
        __builtin_amdgcn_s_setprio(0);
        __builtin_amdgcn_s_barrier();
        __builtin_amdgcn_sched_barrier(0);

        // ---- phase 1: frags B(n2,n3); prefetch next B ----
        #pragma unroll
        for (int n = 2; n < 4; ++n) {
            bH[n] = *(const bf16x8*)(ls + 32768 + bRd + n * 1024);
            bL[n] = *(const bf16x8*)(ls + 49152 + bRd + n * 1024);
        }
        if (kt < NT - 1) {
            u16* v = &lds[nb + 16384 + ch];
            gld16(Bh + offB0 + kn, v);
            gld16(Bh + offB1 + kn, v + 512);
            gld16(Bl + offB0 + kn, v + 8192);
            gld16(Bl + offB1 + kn, v + 8192 + 512);
        }
        __builtin_amdgcn_s_barrier();
        asm volatile("s_waitcnt lgkmcnt(0)" ::: "memory");
        __builtin_amdgcn_sched_barrier(0);
        __builtin_amdgcn_s_setprio(1);
        #pragma unroll
        for (int m = 0; m < 4; ++m)
            #pragma unroll
            for (int n = 2; n < 4; ++n) {
                acc[m][n] = mfma16(aH[m], bH[n], acc[m][n]);
                acc[m][n] = mfma16(aH[m], bL[n], acc[m][n]);
                acc[m][n] = mfma16(aL[m], bH[n], acc[m][n]);
            }
        __builtin_amdgcn_s_setprio(0);
        __builtin_amdgcn_s_barrier();
        __builtin_amdgcn_sched_barrier(0);

        // ---- phase 2: frags A(mh1) ----
        #pragma unroll
        for (int m = 0; m < 4; ++m) {
            aH[m] = *(const bf16x8*)(ls + 4096 + aRd + m * 1024);
            aL[m] = *(const bf16x8*)(ls + 16384 + 4096 + aRd + m * 1024);
        }
        __builtin_amdgcn_s_barrier();
        asm volatile("s_waitcnt lgkmcnt(0)" ::: "memory");
        __builtin_amdgcn_sched_barrier(0);
        __builtin_amdgcn_s_setprio(1);
        #pragma unroll
        for (int m = 0; m < 4; ++m)
            #pragma unroll
            for (int n = 0; n < 2; ++n) {
                acc[4 + m][n] = mfma16(aH[m], bH[n], acc[4 + m][n]);
                acc[4 + m][n] = mfma16(aH[m], bL[n], acc[4 + m][n]);
                acc[4 + m][n] = mfma16(aL[m], bH[n], acc[4 + m][n]);
            }
        __builtin_amdgcn_s_setprio(0);
        __builtin_amdgcn_s_barrier();
        __builtin_amdgcn_sched_barrier(0);

        // ---- phase 3: last quadrant; tile-boundary drain (only vmcnt) ----
        __builtin_amdgcn_s_setprio(1);
        #pragma unroll
        for (int m = 0; m < 4; ++m)
            #pragma unroll
            for (int n = 2; n < 4; ++n) {
                acc[4 + m][n] = mfma16(aH[m], bH[n], acc[4 + m][n]);
                acc[4 + m][n] = mfma16(aH[m], bL[n], acc[4 + m][n]);
                acc[4 + m][n] = mfma16(aL[m], bH[n], acc[4 + m][n]);
            }
        __builtin_amdgcn_s_setprio(0);
        asm volatile("s_waitcnt vmcnt(0)" ::: "memory");
        __builtin_amdgcn_s_barrier();
        __builtin_amdgcn_sched_barrier(0);
    }

    const int rowb = m0 + wm + fq * 4;
    const int colb = n0 + wn + fr;
    #pragma unroll
    for (int mi = 0; mi < 8; ++mi)
        #pragma unroll
        for (int ni = 0; ni < 4; ++ni)
            #pragma unroll
            for (int r = 0; r < 4; ++r)
                C[(size_t)(rowb + mi * 16 + r) * Lk + colb + ni * 16] = acc[mi][ni][r];
}

// -------- softmax: one row per WAVE — no block barriers, shfl-only ---------
__global__ __launch_bounds__(256)
void softmax_wave(float* __restrict__ S, u16* __restrict__ Pb)
{
    const size_t row = (size_t)blockIdx.x * 4 + (threadIdx.x >> 6);
    const int l = threadIdx.x & 63;
    float* p = S + row * (size_t)Lk;

    float4 v[16];
    #pragma unroll
    for (int j = 0; j < 16; ++j) v[j] = ((const float4*)p)[l + j * 64];

    float m = -3.0e38f;
    #pragma unroll
    for (int j = 0; j < 16; ++j)
        m = fmaxf(m, fmaxf(fmaxf(v[j].x, v[j].y), fmaxf(v[j].z, v[j].w)));
    #pragma unroll
    for (int off = 32; off > 0; off >>= 1) m = fmaxf(m, __shfl_xor(m, off));

    float s = 0.f;
    #pragma unroll
    for (int j = 0; j < 16; ++j) {
        v[j].x = __expf(v[j].x - m); s += v[j].x;
        v[j].y = __expf(v[j].y - m); s += v[j].y;
        v[j].z = __expf(v[j].z - m); s += v[j].z;
        v[j].w = __expf(v[j].w - m); s += v[j].w;
    }
    #pragma unroll
    for (int off = 32; off > 0; off >>= 1) s += __shfl_xor(s, off);

    const float inv = 1.0f / s;
    u16* prow = Pb ? Pb + row * (size_t)Lk : nullptr;
    #pragma unroll
    for (int j = 0; j < 16; ++j) {
        v[j].x *= inv; v[j].y *= inv; v[j].z *= inv; v[j].w *= inv;
        ((float4*)p)[l + j * 64] = v[j];
        if (prow) {
            ushort4 h = make_ushort4(f32_to_bf16_rne(v[j].x), f32_to_bf16_rne(v[j].y),
                                     f32_to_bf16_rne(v[j].z), f32_to_bf16_rne(v[j].w));
            ((ushort4*)prow)[l + j * 64] = h;
        }
    }
}

// ------ GEMM2: ctx = P @ V, bf16 NT, BK=64 (half the barrier drains), ------
// XOR-chunk swizzle both-sides (inverse-swizzled global source, swizzled
// ds_read) -> conflict-free frag reads at the 128B row stride.
__global__ __launch_bounds__(256, 3)
void gemm2_mfma(const u16* __restrict__ Pg, const u16* __restrict__ VTg,
                float* __restrict__ Cg)
{
    constexpr int K = Lk;   // 4096
    constexpr int N = D;    // 512
    __shared__ u16 sA[BM * 64];   // 16 KB
    __shared__ u16 sB[BN * 64];   // 16 KB

    const int b = blockIdx.z;
    const u16* A  = Pg  + (size_t)b * Lq * Lk;
    const u16* Bp = VTg + (size_t)b * (size_t)D * Lk;
    float* C = Cg + (size_t)b * Lq * D;

    const int m0 = blockIdx.y * BM;
    const int n0 = blockIdx.x * BN;
    const int t = threadIdx.x, lane = t & 63, wave = t >> 6;
    const int wm = (wave >> 1) * 64, wn = (wave & 1) * 64;
    const int fr = lane & 15, fq = lane >> 4;

    // staging: call j stages LDS chunks (wave*4+j)*64 + lane (16B units).
    // LDS chunk C holds global k-chunk (C&7)^(row&7) of row C>>3.
    const int lr  = lane >> 3;              // row-within-8
    const int gck = (lane & 7) ^ lr;        // inverse-swizzled global k-chunk
    const int gA  = (m0 + wave * 32 + lr) * K + gck * 8;
    const int gB  = (n0 + wave * 32 + lr) * K + gck * 8;

    f32x4 acc[4][4] = {};

    for (int k0 = 0; k0 < K; k0 += 64) {
        if (k0) __syncthreads();
        #pragma unroll
        for (int j = 0; j < 4; ++j) {
            gld16(A  + gA + j * 8 * K + k0, &sA[(wave * 4 + j) * 512]);
            gld16(Bp + gB + j * 8 * K + k0, &sB[(wave * 4 + j) * 512]);
        }
        __syncthreads();

        #pragma unroll
        for (int ks = 0; ks < 2; ++ks) {
            bf16x8 af[4], bf[4];
            #pragma unroll
            for (int x = 0; x < 4; ++x) {
                const int ra = wm + x * 16 + fr;
                const int rb = wn + x * 16 + fr;
                af[x] = *(const bf16x8*)&sA[ra * 64 + ((ks * 4 + fq) ^ (ra & 7)) * 8];
                bf[x] = *(const bf16x8*)&sB[rb * 64 + ((ks * 4 + fq) ^ (rb & 7)) * 8];
            }
            #pragma unroll
            for (int mi = 0; mi < 4; ++mi)
                #pragma unroll
                for (int ni = 0; ni < 4; ++ni)
                    acc[mi][ni] = mfma16(af[mi], bf[ni], acc[mi][ni]);
        }
    }

    #pragma unroll
    for (int mi = 0; mi < 4; ++mi)
        #pragma unroll
        for (int ni = 0; ni < 4; ++ni)
            #pragma unroll
            for (int r = 0; r < 4; ++r) {
                const int row = m0 + wm + mi * 16 + fq * 4 + r;
                const int col = n0 + wn + ni * 16 + fr;
                C[(size_t)row * N + col] = acc[mi][ni][r];
            }
}

// ======================= round-2 fallback kernels ==========================
__global__ __launch_bounds__(256, 2)
void gemm1_r2(const float* __restrict__ Qg, const float* __restrict__ Vg,
              float* __restrict__ Sg)
{
    constexpr int K = D;
    __shared__ alignas(16) u16 sAhi[BM * LDA];
    __shared__ alignas(16) u16 sAlo[BM * LDA];
    __shared__ alignas(16) u16 sBhi[BN * LDA];
    __shared__ alignas(16) u16 sBlo[BN * LDA];

    const int b = blockIdx.z;
    const float* A  = Qg + (size_t)b * Lq * D;
    const float* Bp = Vg + (size_t)b * Lk * D;
    float* C = Sg + (size_t)b * Lq * Lk;

    const int m0 = blockIdx.y * BM;
    const int n0 = blockIdx.x * BN;
    const int t = threadIdx.x, lane = t & 63, wave = t >> 6;
    const int wm = (wave >> 1) * 64, wn = (wave & 1) * 64;
    const int fr = lane & 15, fq = lane >> 4;
    const int sm = t >> 3, sc = t & 7;

    f32x4 acc[4][4] = {};

    for (int k0 = 0; k0 < K; k0 += BK) {
        if (k0) __syncthreads();
        #pragma unroll
        for (int i = 0; i < 4; ++i) {
            const int m = sm + 32 * i;
            const float4 va = *(const float4*)(A  + (size_t)(m0 + m) * K + k0 + sc * 4);
            const float4 vb = *(const float4*)(Bp + (size_t)(n0 + m) * K + k0 + sc * 4);
            uint2 h, l;
            split2(va.x, va.y, h.x, l.x);
            split2(va.z, va.w, h.y, l.y);
            *(uint2*)&sAhi[m * LDA + sc * 4] = h;
            *(uint2*)&sAlo[m * LDA + sc * 4] = l;
            split2(vb.x, vb.y, h.x, l.x);
            split2(vb.z, vb.w, h.y, l.y);
            *(uint2*)&sBhi[m * LDA + sc * 4] = h;
            *(uint2*)&sBlo[m * LDA + sc * 4] = l;
        }
        __syncthreads();

        bf16x8 ah[4], al[4], bh[4], bl[4];
        #pragma unroll
        for (int x = 0; x < 4; ++x) {
            ah[x] = *(const bf16x8*)&sAhi[(wm + x * 16 + fr) * LDA + fq * 8];
            al[x] = *(const bf16x8*)&sAlo[(wm + x * 16 + fr) * LDA + fq * 8];
            bh[x] = *(const bf16x8*)&sBhi[(wn + x * 16 + fr) * LDA + fq * 8];
            bl[x] = *(const bf16x8*)&sBlo[(wn + x * 16 + fr) * LDA + fq * 8];
        }
        #pragma unroll
        for (int mi = 0; mi < 4; ++mi)
            #pragma unroll
            for (int ni = 0; ni < 4; ++ni) {
                acc[mi][ni] = __builtin_amdgcn_mfma_f32_16x16x32_bf16(ah[mi], bh[ni], acc[mi][ni], 0, 0, 0);
                acc[mi][ni] = __builtin_amdgcn_mfma_f32_16x16x32_bf16(ah[mi], bl[ni], acc[mi][ni], 0, 0, 0);
                acc[mi][ni] = __builtin_amdgcn_mfma_f32_16x16x32_bf16(al[mi], bh[ni], acc[mi][ni], 0, 0, 0);
            }
    }

    #pragma unroll
    for (int mi = 0; mi < 4; ++mi)
        #pragma unroll
        for (int ni = 0; ni < 4; ++ni)
            #pragma unroll
            for (int r = 0; r < 4; ++r) {
                const int row = m0 + wm + mi * 16 + fq * 4 + r;
                const int col = n0 + wn + ni * 16 + fr;
                C[(size_t)row * Lk + col] = acc[mi][ni][r];
            }
}

__global__ __launch_bounds__(256, 2)
void gemm2_r2(const float* __restrict__ Pg, const u16* __restrict__ VTg,
              float* __restrict__ Cg)
{
    constexpr int K = Lk;
    constexpr int N = D;
    __shared__ alignas(16) u16 sA[BM * LDA];
    __shared__ alignas(16) u16 sB[BN * LDA];

    const int b = blockIdx.z;
    const float* A  = Pg  + (size_t)b * Lq * Lk;
    const u16*   Bp = VTg + (size_t)b * (size_t)D * Lk;
    float* C = Cg + (size_t)b * Lq * D;

    const int m0 = blockIdx.y * BM;
    const int n0 = blockIdx.x * BN;
    const int t = threadIdx.x, lane = t & 63, wave = t >> 6;
    const int wm = (wave >> 1) * 64, wn = (wave & 1) * 64;
    const int fr = lane & 15, fq = lane >> 4;
    const int sm = t >> 3, sc = t & 7;
    const int bn = t >> 2, bc = t & 3;

    f32x4 acc[4][4] = {};

    for (int k0 = 0; k0 < K; k0 += BK) {
        if (k0) __syncthreads();
        #pragma unroll
        for (int i = 0; i < 4; ++i) {
            const int m = sm + 32 * i;
            const float4 va = *(const float4*)(A + (size_t)(m0 + m) * K + k0 + sc * 4);
            uint2 h;
            h.x = pack2_bf16(va.x, va.y);
            h.y = pack2_bf16(va.z, va.w);
            *(uint2*)&sA[m * LDA + sc * 4] = h;
        }
        #pragma unroll
        for (int i = 0; i < 2; ++i) {
            const int n = bn + 64 * i;
            const bf16x8 vb = *(const bf16x8*)(Bp + (size_t)(n0 + n) * K + k0 + bc * 8);
            *(bf16x8*)&sB[n * LDA + bc * 8] = vb;
        }
        __syncthreads();

        bf16x8 af[4], bf[4];
        #pragma unroll
        for (int x = 0; x < 4; ++x) {
            af[x] = *(const bf16x8*)&sA[(wm + x * 16 + fr) * LDA + fq * 8];
            bf[x] = *(const bf16x8*)&sB[(wn + x * 16 + fr) * LDA + fq * 8];
        }
        #pragma unroll
        for (int mi = 0; mi < 4; ++mi)
            #pragma unroll
            for (int ni = 0; ni < 4; ++ni)
                acc[mi][ni] = __builtin_amdgcn_mfma_f32_16x16x32_bf16(af[mi], bf[ni], acc[mi][ni], 0, 0, 0);
    }

    #pragma unroll
    for (int mi = 0; mi < 4; ++mi)
        #pragma unroll
        for (int ni = 0; ni < 4; ++ni)
            #pragma unroll
            for (int r = 0; r < 4; ++r) {
                const int row = m0 + wm + mi * 16 + fq * 4 + r;
                const int col = n0 + wn + ni * 16 + fr;
                C[(size_t)row * N + col] = acc[mi][ni][r];
            }
}

extern "C" void kernel_launch(void* const* d_in, const int* in_sizes, int n_in,
                              void* d_out, int out_size, void* d_ws, size_t ws_size,
                              hipStream_t stream)
{
    const float* Q = (const float*)d_in[0];   // [B, Lq, D]
    const float* V = (const float*)d_in[1];   // [B, Lk, D]
    float* ctx  = (float*)d_out;                              // [B, Lq, D]
    float* attn = (float*)d_out + (size_t)BATCH * Lq * D;     // [B, Lq, Lk]

    constexpr size_t NQ = (size_t)BATCH * Lq * D;    // 8,388,608 elems
    constexpr size_t NP = (size_t)BATCH * Lq * Lk;   // 67,108,864 elems
    const size_t need = (5 * NQ + NP) * sizeof(u16); // ~208 MiB

    if (ws_size >= need) {
        u16* Qhi = (u16*)d_ws;
        u16* Qlo = Qhi + NQ;
        u16* Vhi = Qlo + NQ;
        u16* Vlo = Vhi + NQ;
        u16* VT  = Vlo + NQ;
        u16* Pb  = VT  + NQ;

        const int n4 = (int)(NQ / 4);
        split_qv_bf16<<<dim3(2 * n4 / 256), 256, 0, stream>>>(Q, V, Qhi, Qlo, Vhi, Vlo, n4);
        transpose_v_bf16<<<dim3(Lk / 32, D / 32, BATCH), 256, 0, stream>>>(V, VT);
        gemm1_8p<<<dim3(Lk / 256, Lq / 256, BATCH), 512, 0, stream>>>(Qhi, Qlo, Vhi, Vlo, attn);
        softmax_wave<<<dim3(BATCH * Lq / 4), 256, 0, stream>>>(attn, Pb);
        gemm2_mfma<<<dim3(D / BN, Lq / BM, BATCH), 256, 0, stream>>>(Pb, VT, ctx);
    } else {
        // round-2 fallback: only needs 16.8 MiB for VT
        u16* VT = (u16*)d_ws;
        transpose_v_bf16<<<dim3(Lk / 32, D / 32, BATCH), 256, 0, stream>>>(V, VT);
        gemm1_r2<<<dim3(Lk / BN, Lq / BM, BATCH), 256, 0, stream>>>(Q, V, attn);
        softmax_wave<<<dim3(BATCH * Lq / 4), 256, 0, stream>>>(attn, nullptr);
        gemm2_r2<<<dim3(D / BN, Lq / BM, BATCH), 256, 0, stream>>>(attn, VT, ctx);
    }
}